// Round 1
// baseline (1097.393 us; speedup 1.0000x reference)
//
#include <hip/hip_runtime.h>
#include <hip/hip_bf16.h>

#define N_NODES 4000
#define N_EDGES 4000
#define T_ALL   8000
#define HID     768

typedef __attribute__((ext_vector_type(8))) short bf16x8;
typedef __attribute__((ext_vector_type(4))) short s16x4;
typedef __attribute__((ext_vector_type(4))) float f32x4;

__device__ __forceinline__ short f2bf(float f) {
    union { float f; unsigned u; } a; a.f = f;
    unsigned u = a.u;
    unsigned r = (u + 0x7fffu + ((u >> 16) & 1u)) >> 16;   // RNE
    return (short)(r & 0xffffu);
}

// ---------------- GEMM: C[M,N] = A[M,K] * B  (B given as BT[N,K]) ----------
// bf16 MFMA, f32 accumulate. 128x128 tile, BK=64, 256 threads (4 waves 2x2).
// Requires: K % 64 == 0, N % 128 == 0. M arbitrary (clamped staging).
template<int BIAS, int RELU>
__global__ __launch_bounds__(256) void gemm_bt(
    const float* __restrict__ A, const float* __restrict__ BT,
    const float* __restrict__ bias, float* __restrict__ C,
    int M, int N, int K, int lda, int ldbt, int ldc)
{
    __shared__ short As[128 * 72];
    __shared__ short Bs[128 * 72];
    const int t    = threadIdx.x;
    const int lane = t & 63;
    const int wave = t >> 6;
    const int wr   = (wave >> 1) << 6;   // 0 or 64
    const int wc   = (wave & 1) << 6;    // 0 or 64
    const int lrow = lane & 15;
    const int kgrp = lane >> 4;          // 0..3
    const int bm0  = blockIdx.x << 7;
    const int bn0  = blockIdx.y << 7;

    f32x4 acc[4][4];
#pragma unroll
    for (int m = 0; m < 4; ++m)
#pragma unroll
        for (int n = 0; n < 4; ++n) acc[m][n] = (f32x4)(0.0f);

    const int nk = K >> 6;
    for (int kt = 0; kt < nk; ++kt) {
        const int k0 = kt << 6;
#pragma unroll
        for (int i = 0; i < 8; ++i) {
            int f   = t + (i << 8);        // 0..2047
            int row = f >> 4;              // 0..127
            int c   = (f & 15) << 2;       // 0..60
            int ga  = bm0 + row; ga = (ga < M) ? ga : (M - 1);
            float4 va = *reinterpret_cast<const float4*>(A + (size_t)ga * lda + k0 + c);
            int gb  = bn0 + row;           // N multiple of 128 -> in range
            float4 vb = *reinterpret_cast<const float4*>(BT + (size_t)gb * ldbt + k0 + c);
            s16x4 sa, sb;
            sa[0] = f2bf(va.x); sa[1] = f2bf(va.y); sa[2] = f2bf(va.z); sa[3] = f2bf(va.w);
            sb[0] = f2bf(vb.x); sb[1] = f2bf(vb.y); sb[2] = f2bf(vb.z); sb[3] = f2bf(vb.w);
            *reinterpret_cast<s16x4*>(&As[row * 72 + c]) = sa;
            *reinterpret_cast<s16x4*>(&Bs[row * 72 + c]) = sb;
        }
        __syncthreads();
#pragma unroll
        for (int kk = 0; kk < 2; ++kk) {
            bf16x8 af[4], bfv[4];
#pragma unroll
            for (int m = 0; m < 4; ++m)
                af[m] = *reinterpret_cast<const bf16x8*>(
                    &As[(wr + m * 16 + lrow) * 72 + kk * 32 + kgrp * 8]);
#pragma unroll
            for (int n = 0; n < 4; ++n)
                bfv[n] = *reinterpret_cast<const bf16x8*>(
                    &Bs[(wc + n * 16 + lrow) * 72 + kk * 32 + kgrp * 8]);
#pragma unroll
            for (int m = 0; m < 4; ++m)
#pragma unroll
                for (int n = 0; n < 4; ++n)
                    acc[m][n] = __builtin_amdgcn_mfma_f32_16x16x32_bf16(
                        af[m], bfv[n], acc[m][n], 0, 0, 0);
        }
        __syncthreads();
    }
    // epilogue: C/D layout col = lane&15, row = (lane>>4)*4 + j
#pragma unroll
    for (int m = 0; m < 4; ++m) {
        int rbase = bm0 + wr + m * 16 + kgrp * 4;
#pragma unroll
        for (int n = 0; n < 4; ++n) {
            int col = bn0 + wc + n * 16 + lrow;
            float bv = BIAS ? bias[col] : 0.0f;
#pragma unroll
            for (int j = 0; j < 4; ++j) {
                int r = rbase + j;
                if (r < M) {
                    float v = acc[m][n][j] + bv;
                    if (RELU) v = fmaxf(v, 0.0f);
                    C[(size_t)r * ldc + col] = v;
                }
            }
        }
    }
}

// ---------------- small kernels -------------------------------------------

// out[N][Kp] = in[K][N]^T, zero-padded to Kp
__global__ void transpose_pad(const float* __restrict__ in, float* __restrict__ out,
                              int K, int N, int Kp)
{
    int i = blockIdx.x * 256 + threadIdx.x;
    if (i >= N * Kp) return;
    int n = i / Kp, k = i % Kp;
    out[i] = (k < K) ? in[k * N + n] : 0.0f;
}

// out[C][R] = in[R][C]^T, R,C multiples of 32
__global__ __launch_bounds__(256) void transpose_f32(const float* __restrict__ in,
                                                     float* __restrict__ out, int R, int C)
{
    __shared__ float tile[32][33];
    int c0 = blockIdx.x << 5;
    int r0 = blockIdx.y << 5;
    int tx = threadIdx.x & 31;
    int ty = threadIdx.x >> 5;
#pragma unroll
    for (int i = ty; i < 32; i += 8)
        tile[i][tx] = in[(size_t)(r0 + i) * C + c0 + tx];
    __syncthreads();
#pragma unroll
    for (int i = ty; i < 32; i += 8)
        out[(size_t)(c0 + i) * R + r0 + tx] = tile[tx][i];
}

__global__ void has_rev_kernel(const int* __restrict__ trans, int* __restrict__ hr, int E)
{
    int e = blockIdx.x;
    int a = trans[e], b = trans[E + e];          // t0[e], t1[e]
    __shared__ int found;
    if (threadIdx.x == 0) found = 0;
    __syncthreads();
    for (int j = threadIdx.x; j < E; j += blockDim.x)
        if (trans[j] == b && trans[E + j] == a) found = 1;   // benign race
    __syncthreads();
    if (threadIdx.x == 0) hr[e] = found;
}

// eraw[e][0..127]: [x[t1] | x[t0] | hr*x[t0] | hr*x[t1] | x[t1]+hr*x[t0] | x[t0]+hr*x[t1] | 0pad]
__global__ void build_eraw(const float* __restrict__ data, const int* __restrict__ trans,
                           const int* __restrict__ hr, float* __restrict__ eraw, int E)
{
    int e = blockIdx.x, c = threadIdx.x;  // blockDim = 32
    int t0 = trans[e], t1 = trans[E + e];
    float* r = eraw + (size_t)e * 128;
    if (c < 20) {
        float x0 = data[t0 * 20 + c];
        float x1 = data[t1 * 20 + c];
        float h  = hr[e] ? 1.0f : 0.0f;
        r[c]       = x1;
        r[20 + c]  = x0;
        r[40 + c]  = h * x0;
        r[60 + c]  = h * x1;
        r[80 + c]  = x1 + h * x0;
        r[100 + c] = x0 + h * x1;
    } else if (c < 28) {
        r[120 + (c - 20)] = 0.0f;
    }
}

// datap[4000][64], cols >= 20 zero
__global__ void pad_data(const float* __restrict__ data, float* __restrict__ dp, int Nn)
{
    int i = blockIdx.x * 256 + threadIdx.x;
    if (i >= Nn * 64) return;
    int r = i >> 6, c = i & 63;
    dp[i] = (c < 20) ? data[r * 20 + c] : 0.0f;
}

// src[i] = (einx[i]==1) ? N_NODES + idx_e : idx_n  (interleave indices)
__global__ void build_src(const int* __restrict__ einx, int* __restrict__ src, int T)
{
    __shared__ int partial[256];
    __shared__ int excl[256];
    int t = threadIdx.x;
    int base = t * 32;
    int cnt = 0;
    for (int i = 0; i < 32; ++i) {
        int idx = base + i;
        if (idx < T) cnt += (einx[idx] == 1);
    }
    partial[t] = cnt;
    __syncthreads();
    if (t == 0) {
        int s = 0;
        for (int i = 0; i < 256; ++i) { excl[i] = s; s += partial[i]; }
    }
    __syncthreads();
    int ce = excl[t];
    int cn = base - ce;
    for (int i = 0; i < 32; ++i) {
        int idx = base + i;
        if (idx >= T) break;
        if (einx[idx] == 1) { src[idx] = N_NODES + ce; ce++; }
        else                { src[idx] = cn; cn++; }
    }
}

__global__ void gather_x(const float* __restrict__ nfeat, const float* __restrict__ efeat,
                         const int* __restrict__ src, float* __restrict__ x)
{
    int i = blockIdx.x * 256 + threadIdx.x;    // over 8000*192 float4s
    int r = i / 192;
    int c = i % 192;
    int s = src[r];
    const float4* rowp = (s >= N_NODES)
        ? reinterpret_cast<const float4*>(efeat + (size_t)(s - N_NODES) * HID)
        : reinterpret_cast<const float4*>(nfeat + (size_t)s * HID);
    reinterpret_cast<float4*>(x)[i] = rowp[c];
}

// hw[T,2] = h1[T,768] @ gcn_w2[768,2] ; one wave per row
__global__ void h1w2_kernel(const float* __restrict__ h1, const float* __restrict__ w2,
                            float* __restrict__ hw)
{
    int wave = threadIdx.x >> 6, lane = threadIdx.x & 63;
    int row = blockIdx.x * 4 + wave;
    const float* hp = h1 + (size_t)row * HID;
    float a0 = 0.0f, a1 = 0.0f;
    for (int k = lane; k < HID; k += 64) {
        float h = hp[k];
        a0 += h * w2[k * 2];
        a1 += h * w2[k * 2 + 1];
    }
    for (int off = 32; off > 0; off >>= 1) {
        a0 += __shfl_down(a0, off);
        a1 += __shfl_down(a1, off);
    }
    if (lane == 0) { hw[row * 2] = a0; hw[row * 2 + 1] = a1; }
}

// logits[T,2] = A[T,T] @ hw[T,2] + b2 ; one block per row
__global__ __launch_bounds__(256) void adj_hw_kernel(const float* __restrict__ A,
    const float* __restrict__ hw, const float* __restrict__ b2, float* __restrict__ logits)
{
    int row = blockIdx.x;
    const float* ar = A + (size_t)row * T_ALL;
    float a0 = 0.0f, a1 = 0.0f;
    for (int k = threadIdx.x; k < T_ALL; k += 256) {
        float v = ar[k];
        a0 += v * hw[k * 2];
        a1 += v * hw[k * 2 + 1];
    }
    __shared__ float s0[256], s1[256];
    s0[threadIdx.x] = a0; s1[threadIdx.x] = a1;
    __syncthreads();
    for (int o = 128; o > 0; o >>= 1) {
        if (threadIdx.x < o) {
            s0[threadIdx.x] += s0[threadIdx.x + o];
            s1[threadIdx.x] += s1[threadIdx.x + o];
        }
        __syncthreads();
    }
    if (threadIdx.x == 0) {
        logits[row * 2]     = s0[0] + b2[0];
        logits[row * 2 + 1] = s1[0] + b2[1];
    }
}

__global__ __launch_bounds__(256) void loss_kernel(const float* __restrict__ logits,
    const int* __restrict__ label, const float* __restrict__ mask, float* __restrict__ outp)
{
    __shared__ float sc[256], sm[256];
    float ac = 0.0f, am = 0.0f;
    for (int i = threadIdx.x; i < T_ALL; i += 256) {
        float l0 = logits[i * 2], l1 = logits[i * 2 + 1];
        float mx = fmaxf(l0, l1);
        float lse = mx + logf(expf(l0 - mx) + expf(l1 - mx));
        float li = label[i] ? l1 : l0;
        float ce = lse - li;
        ac += ce * mask[i];
        am += mask[i];
    }
    sc[threadIdx.x] = ac; sm[threadIdx.x] = am;
    __syncthreads();
    for (int o = 128; o > 0; o >>= 1) {
        if (threadIdx.x < o) {
            sc[threadIdx.x] += sc[threadIdx.x + o];
            sm[threadIdx.x] += sm[threadIdx.x + o];
        }
        __syncthreads();
    }
    if (threadIdx.x == 0) *outp = sc[0] / fmaxf(sm[0], 1.0f);
}

// ---------------- launch ---------------------------------------------------

extern "C" void kernel_launch(void* const* d_in, const int* in_sizes, int n_in,
                              void* d_out, int out_size, void* d_ws, size_t ws_size,
                              hipStream_t stream)
{
    (void)in_sizes; (void)n_in; (void)out_size; (void)ws_size;

    const float* data  = (const float*)d_in[0];
    const float* adj   = (const float*)d_in[2];
    const int*   trans = (const int*)d_in[3];
    const int*   einx  = (const int*)d_in[4];
    const int*   label = (const int*)d_in[5];
    const float* mask  = (const float*)d_in[6];
    const float* w1    = (const float*)d_in[7];
    const float* b1    = (const float*)d_in[8];
    const float* w2    = (const float*)d_in[9];
    const float* b2    = (const float*)d_in[10];
    const float* w21   = (const float*)d_in[11];
    const float* b21   = (const float*)d_in[12];
    const float* w22   = (const float*)d_in[13];
    const float* b22   = (const float*)d_in[14];
    const float* gw1   = (const float*)d_in[15];
    const float* gb1   = (const float*)d_in[16];
    const float* gw2   = (const float*)d_in[17];
    const float* gb2   = (const float*)d_in[18];

    float* ws = (float*)d_ws;
    // workspace layout (floats); all bases multiples of 64 floats (16B-aligned)
    float* w1T   = ws + 0;         // 768*128   =   98304
    float* w2T   = ws + 98304;     // 768*768   =  589824
    float* w21T  = ws + 688128;    // 768*64    =   49152
    float* w22T  = ws + 737280;    // 768*768
    float* gw1T  = ws + 1327104;   // 768*768
    float* eraw  = ws + 1916928;   // 4000*128  =  512000   (region Q start)
    float* datap = ws + 2428928;   // 4000*64   =  256000
    float* C1    = ws + 2684928;   // 4000*768  = 3072000
    float* efeat = ws + 5756928;   // 4000*768
    float* nfeat = ws + 8828928;   // 4000*768
    float* xbuf  = ws + 11900928;  // 8000*768  = 6144000
    float* hwbuf = ws + 18044928;  // 8000*2    =   16000
    int*   hr    = (int*)(ws + 18060928);   // 4000
    int*   src   = (int*)(ws + 18064928);   // 8000
    // aliases (dead-buffer reuse):
    float* xw  = eraw;   // 6,144,000 <= 9,984,000 floats of region Q (all dead by then)
    float* xwT = xbuf;   // transpose reads xw (Q), writes over x (dead)

    float* out    = (float*)d_out;
    float* logits = out;            // [8000,2]
    float* lossp  = out + 16000;    // scalar
    float* h1     = out + 16001;    // [8000,768]

    // 1) weight transposes (BT layouts)
    transpose_pad<<<384, 256, 0, stream>>>(w1, w1T, 120, 768, 128);
    transpose_f32<<<dim3(24, 24), 256, 0, stream>>>(w2, w2T, 768, 768);
    transpose_pad<<<192, 256, 0, stream>>>(w21, w21T, 20, 768, 64);
    transpose_f32<<<dim3(24, 24), 256, 0, stream>>>(w22, w22T, 768, 768);
    transpose_f32<<<dim3(24, 24), 256, 0, stream>>>(gw1, gw1T, 768, 768);

    // 2) edge features
    has_rev_kernel<<<4000, 256, 0, stream>>>(trans, hr, N_EDGES);
    build_eraw<<<4000, 32, 0, stream>>>(data, trans, hr, eraw, N_EDGES);
    pad_data<<<1000, 256, 0, stream>>>(data, datap, N_NODES);

    // 3) MLPs
    gemm_bt<1, 1><<<dim3(32, 6), 256, 0, stream>>>(eraw, w1T, b1, C1, 4000, 768, 128, 128, 128, 768);
    gemm_bt<1, 0><<<dim3(32, 6), 256, 0, stream>>>(C1, w2T, b2, efeat, 4000, 768, 768, 768, 768, 768);
    gemm_bt<1, 1><<<dim3(32, 6), 256, 0, stream>>>(datap, w21T, b21, C1, 4000, 768, 64, 64, 64, 768);
    gemm_bt<1, 0><<<dim3(32, 6), 256, 0, stream>>>(C1, w22T, b22, nfeat, 4000, 768, 768, 768, 768, 768);

    // 4) interleave to x
    build_src<<<1, 256, 0, stream>>>(einx, src, T_ALL);
    gather_x<<<6000, 256, 0, stream>>>(nfeat, efeat, src, xbuf);

    // 5) xw = x @ gcn_w1 ; then transpose for the big GEMM
    gemm_bt<0, 0><<<dim3(63, 6), 256, 0, stream>>>(xbuf, gw1T, nullptr, xw, 8000, 768, 768, 768, 768, 768);
    transpose_f32<<<dim3(24, 250), 256, 0, stream>>>(xw, xwT, 8000, 768);

    // 6) h1 = relu(A @ xw + gb1)  [the 98-GFLOP GEMM]
    gemm_bt<1, 1><<<dim3(63, 6), 256, 0, stream>>>(adj, xwT, gb1, h1, 8000, 768, 8000, 8000, 8000, 768);

    // 7) hw = h1 @ gcn_w2
    h1w2_kernel<<<2000, 256, 0, stream>>>(h1, gw2, hwbuf);

    // 8) logits = A @ hw + gb2
    adj_hw_kernel<<<8000, 256, 0, stream>>>(adj, hwbuf, gb2, logits);

    // 9) loss
    loss_kernel<<<1, 256, 0, stream>>>(logits, label, mask, lossp);
}

// Round 2
// 452.125 us; speedup vs baseline: 2.4272x; 2.4272x over previous
//
#include <hip/hip_runtime.h>
#include <hip/hip_bf16.h>

#define N_NODES 4000
#define N_EDGES 4000
#define T_ALL   8000
#define HID     768

typedef __attribute__((ext_vector_type(8))) short bf16x8;
typedef __attribute__((ext_vector_type(4))) short s16x4;
typedef __attribute__((ext_vector_type(4))) float f32x4;

__device__ __forceinline__ short f2bf(float f) {
    union { float f; unsigned u; } a; a.f = f;
    unsigned u = a.u;
    unsigned r = (u + 0x7fffu + ((u >> 16) & 1u)) >> 16;   // RNE
    return (short)(r & 0xffffu);
}
__device__ __forceinline__ float bf2f(short s) {
    union { unsigned u; float f; } a;
    a.u = ((unsigned)(unsigned short)s) << 16;
    return a.f;
}
__device__ __forceinline__ void gload_lds16(const void* g, void* l) {
    __builtin_amdgcn_global_load_lds(
        (const __attribute__((address_space(1))) void*)g,
        (__attribute__((address_space(3))) void*)l, 16, 0, 0);
}

// ---------------- GEMM: C[M,N] = A[M,K] * B  (B given as BT[N,K], bf16) ----
// 128x128 tile, BK=64, 256 threads (4 waves 2x2). K%64==0, N%128==0, M any.
// AF32=0: A bf16, staged via global_load_lds (swizzled source).
// AF32=1: A f32, reg-staged + converted (fallback when ws too small for bf16 adj).
template<int BIAS, int RELU, int OUTBF, int AF32>
__global__ __launch_bounds__(256) void gemm_bf(
    const void* __restrict__ Av, const short* __restrict__ BT,
    const float* __restrict__ bias, void* __restrict__ Cv,
    int M, int N, int K, int lda, int ldbt, int ldc)
{
    __shared__ __align__(16) short As[128 * 64];
    __shared__ __align__(16) short Bs[128 * 64];
    const int t    = threadIdx.x;
    const int lane = t & 63;
    const int wave = t >> 6;
    const int wr   = (wave >> 1) << 6;
    const int wc   = (wave & 1) << 6;
    const int lrow = lane & 15;
    const int kgrp = lane >> 4;
    const int bm0  = blockIdx.x << 7;
    const int bn0  = blockIdx.y << 7;
    const short* Ab = (const short*)Av;
    const float* Af = (const float*)Av;

    f32x4 acc[4][4];
#pragma unroll
    for (int m = 0; m < 4; ++m)
#pragma unroll
        for (int n = 0; n < 4; ++n) acc[m][n] = (f32x4)(0.0f);

    const int nk = K >> 6;
    for (int kt = 0; kt < nk; ++kt) {
        const int k0 = kt << 6;
        // B: async global->LDS, source pre-swizzled (slot ^= row&7)
#pragma unroll
        for (int i = 0; i < 4; ++i) {
            int f = t + (i << 8);
            int row = f >> 3, slot = f & 7;
            const short* gp = BT + (size_t)(bn0 + row) * ldbt + k0 + ((slot ^ (row & 7)) << 3);
            gload_lds16(gp, &Bs[((i << 8) + (wave << 6)) * 8]);
        }
        if constexpr (!AF32) {
#pragma unroll
            for (int i = 0; i < 4; ++i) {
                int f = t + (i << 8);
                int row = f >> 3, slot = f & 7;
                int ga = bm0 + row; ga = (ga < M) ? ga : (M - 1);
                const short* gp = Ab + (size_t)ga * lda + k0 + ((slot ^ (row & 7)) << 3);
                gload_lds16(gp, &As[((i << 8) + (wave << 6)) * 8]);
            }
        } else {
#pragma unroll
            for (int i = 0; i < 4; ++i) {
                int f = t + (i << 8);
                int row = f >> 3, c8 = f & 7;
                int ga = bm0 + row; ga = (ga < M) ? ga : (M - 1);
                const float* ap = Af + (size_t)ga * lda + k0 + (c8 << 3);
                float4 v0 = *reinterpret_cast<const float4*>(ap);
                float4 v1 = *reinterpret_cast<const float4*>(ap + 4);
                union { bf16x8 v; short s[8]; } u;
                u.s[0] = f2bf(v0.x); u.s[1] = f2bf(v0.y); u.s[2] = f2bf(v0.z); u.s[3] = f2bf(v0.w);
                u.s[4] = f2bf(v1.x); u.s[5] = f2bf(v1.y); u.s[6] = f2bf(v1.z); u.s[7] = f2bf(v1.w);
                *reinterpret_cast<bf16x8*>(&As[row * 64 + ((c8 ^ (row & 7)) << 3)]) = u.v;
            }
        }
        __syncthreads();
#pragma unroll
        for (int kk = 0; kk < 2; ++kk) {
            bf16x8 af[4], bfv[4];
#pragma unroll
            for (int m = 0; m < 4; ++m) {
                int r = wr + m * 16 + lrow;
                af[m] = *reinterpret_cast<const bf16x8*>(
                    &As[r * 64 + (((kk * 4 + kgrp) ^ (r & 7)) << 3)]);
            }
#pragma unroll
            for (int n = 0; n < 4; ++n) {
                int r = wc + n * 16 + lrow;
                bfv[n] = *reinterpret_cast<const bf16x8*>(
                    &Bs[r * 64 + (((kk * 4 + kgrp) ^ (r & 7)) << 3)]);
            }
#pragma unroll
            for (int m = 0; m < 4; ++m)
#pragma unroll
                for (int n = 0; n < 4; ++n)
                    acc[m][n] = __builtin_amdgcn_mfma_f32_16x16x32_bf16(
                        af[m], bfv[n], acc[m][n], 0, 0, 0);
        }
        __syncthreads();
    }
    // epilogue: C/D layout col = lane&15, row = (lane>>4)*4 + j
#pragma unroll
    for (int m = 0; m < 4; ++m) {
        int rbase = bm0 + wr + m * 16 + kgrp * 4;
#pragma unroll
        for (int n = 0; n < 4; ++n) {
            int col = bn0 + wc + n * 16 + lrow;
            float bv = BIAS ? bias[col] : 0.0f;
#pragma unroll
            for (int j = 0; j < 4; ++j) {
                int r = rbase + j;
                if (r < M) {
                    float v = acc[m][n][j] + bv;
                    if (RELU) v = fmaxf(v, 0.0f);
                    if (OUTBF) ((short*)Cv)[(size_t)r * ldc + col] = f2bf(v);
                    else       ((float*)Cv)[(size_t)r * ldc + col] = v;
                }
            }
        }
    }
}

// ---------------- small kernels -------------------------------------------

// out[N][Kp] = bf16(in[K][N]^T), zero-padded rows K..Kp
__global__ void transpose_pad_bf(const float* __restrict__ in, short* __restrict__ out,
                                 int K, int N, int Kp)
{
    int i = blockIdx.x * 256 + threadIdx.x;
    if (i >= N * Kp) return;
    int n = i / Kp, k = i % Kp;
    out[i] = (k < K) ? f2bf(in[k * N + n]) : (short)0;
}

// out[C][R] = bf16(in[R][C]^T), R,C multiples of 32
__global__ __launch_bounds__(256) void transpose_f2b(const float* __restrict__ in,
                                                     short* __restrict__ out, int R, int C)
{
    __shared__ float tile[32][33];
    int c0 = blockIdx.x << 5, r0 = blockIdx.y << 5;
    int tx = threadIdx.x & 31, ty = threadIdx.x >> 5;
#pragma unroll
    for (int i = ty; i < 32; i += 8)
        tile[i][tx] = in[(size_t)(r0 + i) * C + c0 + tx];
    __syncthreads();
#pragma unroll
    for (int i = ty; i < 32; i += 8)
        out[(size_t)(c0 + i) * R + r0 + tx] = f2bf(tile[tx][i]);
}

// bf16 transpose: out[C][R] = in[R][C]^T
__global__ __launch_bounds__(256) void transpose_bf(const short* __restrict__ in,
                                                    short* __restrict__ out, int R, int C)
{
    __shared__ short tile[32][33];
    int c0 = blockIdx.x << 5, r0 = blockIdx.y << 5;
    int tx = threadIdx.x & 31, ty = threadIdx.x >> 5;
#pragma unroll
    for (int i = ty; i < 32; i += 8)
        tile[i][tx] = in[(size_t)(r0 + i) * C + c0 + tx];
    __syncthreads();
#pragma unroll
    for (int i = ty; i < 32; i += 8)
        out[(size_t)(c0 + i) * R + r0 + tx] = tile[tx][i];
}

// f32 -> bf16, 8 elems/thread
__global__ void cvt_bf16(const float* __restrict__ in, short* __restrict__ out, int n8)
{
    int i = blockIdx.x * 256 + threadIdx.x;
    if (i >= n8) return;
    float4 v0 = *reinterpret_cast<const float4*>(in + (size_t)i * 8);
    float4 v1 = *reinterpret_cast<const float4*>(in + (size_t)i * 8 + 4);
    union { bf16x8 v; short s[8]; } u;
    u.s[0] = f2bf(v0.x); u.s[1] = f2bf(v0.y); u.s[2] = f2bf(v0.z); u.s[3] = f2bf(v0.w);
    u.s[4] = f2bf(v1.x); u.s[5] = f2bf(v1.y); u.s[6] = f2bf(v1.z); u.s[7] = f2bf(v1.w);
    *reinterpret_cast<bf16x8*>(out + (size_t)i * 8) = u.v;
}

__global__ void has_rev_kernel(const int* __restrict__ trans, int* __restrict__ hr, int E)
{
    int e = blockIdx.x;
    int a = trans[e], b = trans[E + e];
    __shared__ int found;
    if (threadIdx.x == 0) found = 0;
    __syncthreads();
    for (int j = threadIdx.x; j < E; j += blockDim.x)
        if (trans[j] == b && trans[E + j] == a) found = 1;   // benign race
    __syncthreads();
    if (threadIdx.x == 0) hr[e] = found;
}

__global__ void build_eraw(const float* __restrict__ data, const int* __restrict__ trans,
                           const int* __restrict__ hr, short* __restrict__ eraw, int E)
{
    int e = blockIdx.x, c = threadIdx.x;  // blockDim = 32
    int t0 = trans[e], t1 = trans[E + e];
    short* r = eraw + (size_t)e * 128;
    if (c < 20) {
        float x0 = data[t0 * 20 + c];
        float x1 = data[t1 * 20 + c];
        float h  = hr[e] ? 1.0f : 0.0f;
        r[c]       = f2bf(x1);
        r[20 + c]  = f2bf(x0);
        r[40 + c]  = f2bf(h * x0);
        r[60 + c]  = f2bf(h * x1);
        r[80 + c]  = f2bf(x1 + h * x0);
        r[100 + c] = f2bf(x0 + h * x1);
    } else if (c < 28) {
        r[120 + (c - 20)] = 0;
    }
}

__global__ void pad_data(const float* __restrict__ data, short* __restrict__ dp, int Nn)
{
    int i = blockIdx.x * 256 + threadIdx.x;
    if (i >= Nn * 64) return;
    int r = i >> 6, c = i & 63;
    dp[i] = (c < 20) ? f2bf(data[r * 20 + c]) : (short)0;
}

__global__ void build_src(const int* __restrict__ einx, int* __restrict__ src, int T)
{
    __shared__ int partial[256];
    __shared__ int excl[256];
    int t = threadIdx.x;
    int base = t * 32;
    int cnt = 0;
    for (int i = 0; i < 32; ++i) {
        int idx = base + i;
        if (idx < T) cnt += (einx[idx] == 1);
    }
    partial[t] = cnt;
    __syncthreads();
    if (t == 0) {
        int s = 0;
        for (int i = 0; i < 256; ++i) { excl[i] = s; s += partial[i]; }
    }
    __syncthreads();
    int ce = excl[t];
    int cn = base - ce;
    for (int i = 0; i < 32; ++i) {
        int idx = base + i;
        if (idx >= T) break;
        if (einx[idx] == 1) { src[idx] = N_NODES + ce; ce++; }
        else                { src[idx] = cn; cn++; }
    }
}

__global__ void gather_x(const short* __restrict__ nfeat, const short* __restrict__ efeat,
                         const int* __restrict__ src, short* __restrict__ x)
{
    int i = blockIdx.x * 256 + threadIdx.x;    // over 8000*96 bf16x8 chunks
    int r = i / 96, c = i % 96;
    int s = src[r];
    const bf16x8* rowp = (s >= N_NODES)
        ? reinterpret_cast<const bf16x8*>(efeat + (size_t)(s - N_NODES) * HID)
        : reinterpret_cast<const bf16x8*>(nfeat + (size_t)s * HID);
    reinterpret_cast<bf16x8*>(x)[i] = rowp[c];
}

// hw[T,2] = h1[T,768] @ gcn_w2[768,2] ; one wave per row
__global__ void h1w2_kernel(const float* __restrict__ h1, const float* __restrict__ w2,
                            float* __restrict__ hw)
{
    int wave = threadIdx.x >> 6, lane = threadIdx.x & 63;
    int row = blockIdx.x * 4 + wave;
    const float* hp = h1 + (size_t)row * HID;
    float a0 = 0.0f, a1 = 0.0f;
    for (int k = lane; k < HID; k += 64) {
        float h = hp[k];
        a0 += h * w2[k * 2];
        a1 += h * w2[k * 2 + 1];
    }
    for (int off = 32; off > 0; off >>= 1) {
        a0 += __shfl_down(a0, off);
        a1 += __shfl_down(a1, off);
    }
    if (lane == 0) { hw[row * 2] = a0; hw[row * 2 + 1] = a1; }
}

// logits[T,2] = A_bf[T,T] @ hw[T,2] + b2 ; one block per row
__global__ __launch_bounds__(256) void adj_hw_bf(const short* __restrict__ A,
    const float* __restrict__ hw, const float* __restrict__ b2, float* __restrict__ logits)
{
    int row = blockIdx.x;
    const short* ar = A + (size_t)row * T_ALL;
    float a0 = 0.0f, a1 = 0.0f;
    for (int c = threadIdx.x; c < 1000; c += 256) {
        bf16x8 v = *reinterpret_cast<const bf16x8*>(ar + c * 8);
#pragma unroll
        for (int j = 0; j < 8; ++j) {
            float av = bf2f(v[j]);
            int k = c * 8 + j;
            a0 += av * hw[k * 2];
            a1 += av * hw[k * 2 + 1];
        }
    }
    __shared__ float s0[256], s1[256];
    s0[threadIdx.x] = a0; s1[threadIdx.x] = a1;
    __syncthreads();
    for (int o = 128; o > 0; o >>= 1) {
        if (threadIdx.x < o) {
            s0[threadIdx.x] += s0[threadIdx.x + o];
            s1[threadIdx.x] += s1[threadIdx.x + o];
        }
        __syncthreads();
    }
    if (threadIdx.x == 0) {
        logits[row * 2]     = s0[0] + b2[0];
        logits[row * 2 + 1] = s1[0] + b2[1];
    }
}

__global__ __launch_bounds__(256) void adj_hw_f32(const float* __restrict__ A,
    const float* __restrict__ hw, const float* __restrict__ b2, float* __restrict__ logits)
{
    int row = blockIdx.x;
    const float* ar = A + (size_t)row * T_ALL;
    float a0 = 0.0f, a1 = 0.0f;
    for (int k = threadIdx.x; k < T_ALL; k += 256) {
        float v = ar[k];
        a0 += v * hw[k * 2];
        a1 += v * hw[k * 2 + 1];
    }
    __shared__ float s0[256], s1[256];
    s0[threadIdx.x] = a0; s1[threadIdx.x] = a1;
    __syncthreads();
    for (int o = 128; o > 0; o >>= 1) {
        if (threadIdx.x < o) {
            s0[threadIdx.x] += s0[threadIdx.x + o];
            s1[threadIdx.x] += s1[threadIdx.x + o];
        }
        __syncthreads();
    }
    if (threadIdx.x == 0) {
        logits[row * 2]     = s0[0] + b2[0];
        logits[row * 2 + 1] = s1[0] + b2[1];
    }
}

__global__ __launch_bounds__(256) void loss_kernel(const float* __restrict__ logits,
    const int* __restrict__ label, const float* __restrict__ mask, float* __restrict__ outp)
{
    __shared__ float sc[256], sm[256];
    float ac = 0.0f, am = 0.0f;
    for (int i = threadIdx.x; i < T_ALL; i += 256) {
        float l0 = logits[i * 2], l1 = logits[i * 2 + 1];
        float mx = fmaxf(l0, l1);
        float lse = mx + logf(expf(l0 - mx) + expf(l1 - mx));
        float li = label[i] ? l1 : l0;
        ac += (lse - li) * mask[i];
        am += mask[i];
    }
    sc[threadIdx.x] = ac; sm[threadIdx.x] = am;
    __syncthreads();
    for (int o = 128; o > 0; o >>= 1) {
        if (threadIdx.x < o) {
            sc[threadIdx.x] += sc[threadIdx.x + o];
            sm[threadIdx.x] += sm[threadIdx.x + o];
        }
        __syncthreads();
    }
    if (threadIdx.x == 0) *outp = sc[0] / fmaxf(sm[0], 1.0f);
}

// ---------------- launch ---------------------------------------------------

extern "C" void kernel_launch(void* const* d_in, const int* in_sizes, int n_in,
                              void* d_out, int out_size, void* d_ws, size_t ws_size,
                              hipStream_t stream)
{
    (void)in_sizes; (void)n_in; (void)out_size;

    const float* data  = (const float*)d_in[0];
    const float* adj   = (const float*)d_in[2];
    const int*   trans = (const int*)d_in[3];
    const int*   einx  = (const int*)d_in[4];
    const int*   label = (const int*)d_in[5];
    const float* mask  = (const float*)d_in[6];
    const float* w1    = (const float*)d_in[7];
    const float* b1    = (const float*)d_in[8];
    const float* w2    = (const float*)d_in[9];
    const float* b2    = (const float*)d_in[10];
    const float* w21   = (const float*)d_in[11];
    const float* b21   = (const float*)d_in[12];
    const float* w22   = (const float*)d_in[13];
    const float* b22   = (const float*)d_in[14];
    const float* gw1   = (const float*)d_in[15];
    const float* gb1   = (const float*)d_in[16];
    const float* gw2   = (const float*)d_in[17];
    const float* gb2   = (const float*)d_in[18];

    char* W = (char*)d_ws;
    // transient low region (all dead before adj bf16 conversion in full path)
    short* w1T   = (short*)(W + 0);          // 768*128
    short* w2T   = (short*)(W + 196608);     // 768*768
    short* w21T  = (short*)(W + 1376256);    // 768*64
    short* w22T  = (short*)(W + 1474560);    // 768*768
    short* gw1T  = (short*)(W + 2654208);    // 768*768
    short* eraw  = (short*)(W + 3833856);    // 4000*128
    short* datap = (short*)(W + 4857856);    // 4000*64
    short* C1    = (short*)(W + 5369856);    // 4000*768
    short* efeat = (short*)(W + 11513856);   // 4000*768
    short* nfeat = (short*)(W + 17657856);   // 4000*768
    short* xbuf  = (short*)(W + 23801856);   // 8000*768
    short* xw    = (short*)(W + 36089856);   // 8000*768
    int*   hr    = (int*)(W + 48377856);     // 4000
    int*   src   = (int*)(W + 48393856);     // 8000

    const bool big = (ws_size >= (size_t)140352000);
    short* adjbf = (short*)W;                // full path only: [0, 128MB)
    short* xwT;  float* hwbuf;
    if (big) {
        xwT   = (short*)(W + 128000000);     // 768*8000 bf16
        hwbuf = (float*)(W + 140288000);     // 8000*2 f32
    } else {
        xwT   = (short*)(W + 48425856);
        hwbuf = (float*)(W + 60713856);
    }

    float* out    = (float*)d_out;
    float* logits = out;            // [8000,2]
    float* lossp  = out + 16000;    // scalar
    float* h1     = out + 16001;    // [8000,768]

    // 1) weight transposes -> bf16 BT layouts
    transpose_pad_bf<<<384, 256, 0, stream>>>(w1, w1T, 120, 768, 128);
    transpose_f2b<<<dim3(24, 24), 256, 0, stream>>>(w2, w2T, 768, 768);
    transpose_pad_bf<<<192, 256, 0, stream>>>(w21, w21T, 20, 768, 64);
    transpose_f2b<<<dim3(24, 24), 256, 0, stream>>>(w22, w22T, 768, 768);
    transpose_f2b<<<dim3(24, 24), 256, 0, stream>>>(gw1, gw1T, 768, 768);

    // 2) edge/node features (bf16)
    has_rev_kernel<<<4000, 256, 0, stream>>>(trans, hr, N_EDGES);
    build_eraw<<<4000, 32, 0, stream>>>(data, trans, hr, eraw, N_EDGES);
    pad_data<<<1000, 256, 0, stream>>>(data, datap, N_NODES);

    // 3) MLPs (bf16 in, bf16 out)
    gemm_bf<1, 1, 1, 0><<<dim3(32, 6), 256, 0, stream>>>(eraw, w1T, b1, C1, 4000, 768, 128, 128, 128, 768);
    gemm_bf<1, 0, 1, 0><<<dim3(32, 6), 256, 0, stream>>>(C1, w2T, b2, efeat, 4000, 768, 768, 768, 768, 768);
    gemm_bf<1, 1, 1, 0><<<dim3(32, 6), 256, 0, stream>>>(datap, w21T, b21, C1, 4000, 768, 64, 64, 64, 768);
    gemm_bf<1, 0, 1, 0><<<dim3(32, 6), 256, 0, stream>>>(C1, w22T, b22, nfeat, 4000, 768, 768, 768, 768, 768);

    // 4) interleave to x (bf16)
    build_src<<<1, 256, 0, stream>>>(einx, src, T_ALL);
    gather_x<<<3000, 256, 0, stream>>>(nfeat, efeat, src, xbuf);

    // 5) xw = x @ gcn_w1 (bf16) ; transpose to xwT[768][8000]
    gemm_bf<0, 0, 1, 0><<<dim3(63, 6), 256, 0, stream>>>(xbuf, gw1T, nullptr, xw, 8000, 768, 768, 768, 768, 768);
    transpose_bf<<<dim3(24, 250), 256, 0, stream>>>(xw, xwT, 8000, 768);

    if (big) {
        // 6a) adj -> bf16 (overwrites transient region; everything there is dead)
        cvt_bf16<<<31250, 256, 0, stream>>>(adj, adjbf, 8000000);
        // 7) h1 = relu(adj_bf @ xw + gb1)  [98 GFLOP]
        gemm_bf<1, 1, 0, 0><<<dim3(63, 6), 256, 0, stream>>>(adjbf, xwT, gb1, h1, 8000, 768, 8000, 8000, 8000, 768);
        h1w2_kernel<<<2000, 256, 0, stream>>>(h1, gw2, hwbuf);
        adj_hw_bf<<<8000, 256, 0, stream>>>(adjbf, hwbuf, gb2, logits);
    } else {
        gemm_bf<1, 1, 0, 1><<<dim3(63, 6), 256, 0, stream>>>(adj, xwT, gb1, h1, 8000, 768, 8000, 8000, 8000, 768);
        h1w2_kernel<<<2000, 256, 0, stream>>>(h1, gw2, hwbuf);
        adj_hw_f32<<<8000, 256, 0, stream>>>(adj, hwbuf, gb2, logits);
    }
    loss_kernel<<<1, 256, 0, stream>>>(logits, label, mask, lossp);
}

// Round 3
// 437.351 us; speedup vs baseline: 2.5092x; 1.0338x over previous
//
#include <hip/hip_runtime.h>
#include <hip/hip_bf16.h>

#define N_NODES 4000
#define N_EDGES 4000
#define T_ALL   8000
#define HID     768

typedef __attribute__((ext_vector_type(8))) short bf16x8;
typedef __attribute__((ext_vector_type(4))) float f32x4;

__device__ __forceinline__ short f2bf(float f) {
    union { float f; unsigned u; } a; a.f = f;
    unsigned u = a.u;
    unsigned r = (u + 0x7fffu + ((u >> 16) & 1u)) >> 16;   // RNE
    return (short)(r & 0xffffu);
}
__device__ __forceinline__ float bf2f(short s) {
    union { unsigned u; float f; } a;
    a.u = ((unsigned)(unsigned short)s) << 16;
    return a.f;
}
__device__ __forceinline__ void gload_lds16(const void* g, void* l) {
    __builtin_amdgcn_global_load_lds(
        (const __attribute__((address_space(1))) void*)g,
        (__attribute__((address_space(3))) void*)l, 16, 0, 0);
}

// ---------------- GEMM: C[M,N] = A[M,K] * B  (B given as BT[N,K], bf16) ----
// 128x128 tile, BK=64, 256 threads (4 waves 2x2), double-buffered LDS.
// Grid: x = N-blocks (fastest, for A-row reuse in L2/L3), y = M-blocks,
// z = K-splits (SPLIT=1). K%64==0. M,N arbitrary (clamped staging + guards).
// AF32=1: A is f32, reg-staged + converted (fallback path).
// SPLIT=1: write bf16 partials at Cv + z*M*ldc, no bias/relu.
template<int BIAS, int RELU, int OUTBF, int AF32, int SPLIT>
__global__ __launch_bounds__(256) void gemm_bf(
    const void* __restrict__ Av, const short* __restrict__ BT,
    const float* __restrict__ bias, void* __restrict__ Cv,
    int M, int N, int K, int lda, int ldbt, int ldc, int kc64)
{
    __shared__ __align__(16) short As[2][128 * 64];
    __shared__ __align__(16) short Bs[2][128 * 64];
    const int t    = threadIdx.x;
    const int lane = t & 63;
    const int wave = t >> 6;
    const int wr   = (wave >> 1) << 6;
    const int wc   = (wave & 1) << 6;
    const int lrow = lane & 15;
    const int kgrp = lane >> 4;
    const int bm0  = blockIdx.y << 7;
    const int bn0  = blockIdx.x << 7;
    const short* Ab = (const short*)Av;
    const float* Af = (const float*)Av;

    int kbeg = 0, nk = K >> 6;
    if constexpr (SPLIT) {
        kbeg = blockIdx.z * kc64 * 64;
        int rem = (K - kbeg) >> 6;
        nk = rem < kc64 ? rem : kc64;
    }

    auto stage = [&](int kt, int buf) {
        const int k0 = kbeg + (kt << 6);
#pragma unroll
        for (int i = 0; i < 4; ++i) {
            int f = t + (i << 8);
            int row = f >> 3, slot = f & 7;
            int gb = bn0 + row; gb = (gb < N) ? gb : (N - 1);
            gload_lds16(BT + (size_t)gb * ldbt + k0 + ((slot ^ (row & 7)) << 3),
                        &Bs[buf][((i << 8) + (wave << 6)) * 8]);
        }
        if constexpr (!AF32) {
#pragma unroll
            for (int i = 0; i < 4; ++i) {
                int f = t + (i << 8);
                int row = f >> 3, slot = f & 7;
                int ga = bm0 + row; ga = (ga < M) ? ga : (M - 1);
                gload_lds16(Ab + (size_t)ga * lda + k0 + ((slot ^ (row & 7)) << 3),
                            &As[buf][((i << 8) + (wave << 6)) * 8]);
            }
        } else {
#pragma unroll
            for (int i = 0; i < 4; ++i) {
                int f = t + (i << 8);
                int row = f >> 3, c8 = f & 7;
                int ga = bm0 + row; ga = (ga < M) ? ga : (M - 1);
                const float* ap = Af + (size_t)ga * lda + k0 + (c8 << 3);
                float4 v0 = *reinterpret_cast<const float4*>(ap);
                float4 v1 = *reinterpret_cast<const float4*>(ap + 4);
                union { bf16x8 v; short s[8]; } u;
                u.s[0] = f2bf(v0.x); u.s[1] = f2bf(v0.y); u.s[2] = f2bf(v0.z); u.s[3] = f2bf(v0.w);
                u.s[4] = f2bf(v1.x); u.s[5] = f2bf(v1.y); u.s[6] = f2bf(v1.z); u.s[7] = f2bf(v1.w);
                *reinterpret_cast<bf16x8*>(&As[buf][row * 64 + ((c8 ^ (row & 7)) << 3)]) = u.v;
            }
        }
    };

    f32x4 acc[4][4];
#pragma unroll
    for (int m = 0; m < 4; ++m)
#pragma unroll
        for (int n = 0; n < 4; ++n) acc[m][n] = (f32x4)(0.0f);

    stage(0, 0);
    __syncthreads();
    int cur = 0;
    for (int kt = 0; kt < nk; ++kt) {
        if (kt + 1 < nk) stage(kt + 1, cur ^ 1);
#pragma unroll
        for (int kk = 0; kk < 2; ++kk) {
            bf16x8 af[4], bfv[4];
#pragma unroll
            for (int m = 0; m < 4; ++m) {
                int r = wr + m * 16 + lrow;
                af[m] = *reinterpret_cast<const bf16x8*>(
                    &As[cur][r * 64 + (((kk * 4 + kgrp) ^ (r & 7)) << 3)]);
            }
#pragma unroll
            for (int n = 0; n < 4; ++n) {
                int r = wc + n * 16 + lrow;
                bfv[n] = *reinterpret_cast<const bf16x8*>(
                    &Bs[cur][r * 64 + (((kk * 4 + kgrp) ^ (r & 7)) << 3)]);
            }
#pragma unroll
            for (int m = 0; m < 4; ++m)
#pragma unroll
                for (int n = 0; n < 4; ++n)
                    acc[m][n] = __builtin_amdgcn_mfma_f32_16x16x32_bf16(
                        af[m], bfv[n], acc[m][n], 0, 0, 0);
        }
        __syncthreads();
        cur ^= 1;
    }

    // epilogue: C/D layout col = lane&15, row = (lane>>4)*4 + j
    short* Cb = (short*)Cv;
    float* Cf = (float*)Cv;
    if constexpr (SPLIT) Cb += (size_t)blockIdx.z * M * ldc;
#pragma unroll
    for (int m = 0; m < 4; ++m) {
        int rbase = bm0 + wr + m * 16 + kgrp * 4;
#pragma unroll
        for (int n = 0; n < 4; ++n) {
            int col = bn0 + wc + n * 16 + lrow;
            if (col >= N) continue;
            float bv = BIAS ? bias[col] : 0.0f;
#pragma unroll
            for (int j = 0; j < 4; ++j) {
                int r = rbase + j;
                if (r < M) {
                    float v = acc[m][n][j] + bv;
                    if (RELU) v = fmaxf(v, 0.0f);
                    if (OUTBF) Cb[(size_t)r * ldc + col] = f2bf(v);
                    else       Cf[(size_t)r * ldc + col] = v;
                }
            }
        }
    }
}

// h1 = relu(sum_z partial_z + bias), partials bf16 [4][8000*768], out f32
__global__ void reduce4_bias_relu(const short* __restrict__ p,
                                  const float* __restrict__ bias,
                                  float* __restrict__ h1)
{
    int i = blockIdx.x * 256 + threadIdx.x;     // 8-elem chunks
    if (i >= 768000) return;
    size_t off = (size_t)i * 8;
    int col0 = (int)(off % 768);
    float acc[8];
#pragma unroll
    for (int j = 0; j < 8; ++j) acc[j] = bias[col0 + j];
#pragma unroll
    for (int z = 0; z < 4; ++z) {
        bf16x8 v = *reinterpret_cast<const bf16x8*>(p + (size_t)z * 6144000 + off);
#pragma unroll
        for (int j = 0; j < 8; ++j) acc[j] += bf2f(v[j]);
    }
    float4 o0 = make_float4(fmaxf(acc[0], 0.f), fmaxf(acc[1], 0.f), fmaxf(acc[2], 0.f), fmaxf(acc[3], 0.f));
    float4 o1 = make_float4(fmaxf(acc[4], 0.f), fmaxf(acc[5], 0.f), fmaxf(acc[6], 0.f), fmaxf(acc[7], 0.f));
    *reinterpret_cast<float4*>(h1 + off)     = o0;
    *reinterpret_cast<float4*>(h1 + off + 4) = o1;
}

// ---------------- small kernels -------------------------------------------

__global__ void transpose_pad_bf(const float* __restrict__ in, short* __restrict__ out,
                                 int K, int N, int Kp)
{
    int i = blockIdx.x * 256 + threadIdx.x;
    if (i >= N * Kp) return;
    int n = i / Kp, k = i % Kp;
    out[i] = (k < K) ? f2bf(in[k * N + n]) : (short)0;
}

__global__ __launch_bounds__(256) void transpose_f2b(const float* __restrict__ in,
                                                     short* __restrict__ out, int R, int C)
{
    __shared__ float tile[32][33];
    int c0 = blockIdx.x << 5, r0 = blockIdx.y << 5;
    int tx = threadIdx.x & 31, ty = threadIdx.x >> 5;
#pragma unroll
    for (int i = ty; i < 32; i += 8)
        tile[i][tx] = in[(size_t)(r0 + i) * C + c0 + tx];
    __syncthreads();
#pragma unroll
    for (int i = ty; i < 32; i += 8)
        out[(size_t)(c0 + i) * R + r0 + tx] = f2bf(tile[tx][i]);
}

__global__ void cvt_bf16(const float* __restrict__ in, short* __restrict__ out, int n8)
{
    int i = blockIdx.x * 256 + threadIdx.x;
    if (i >= n8) return;
    float4 v0 = *reinterpret_cast<const float4*>(in + (size_t)i * 8);
    float4 v1 = *reinterpret_cast<const float4*>(in + (size_t)i * 8 + 4);
    union { bf16x8 v; short s[8]; } u;
    u.s[0] = f2bf(v0.x); u.s[1] = f2bf(v0.y); u.s[2] = f2bf(v0.z); u.s[3] = f2bf(v0.w);
    u.s[4] = f2bf(v1.x); u.s[5] = f2bf(v1.y); u.s[6] = f2bf(v1.z); u.s[7] = f2bf(v1.w);
    *reinterpret_cast<bf16x8*>(out + (size_t)i * 8) = u.v;
}

__global__ void has_rev_kernel(const int* __restrict__ trans, int* __restrict__ hr, int E)
{
    int e = blockIdx.x;
    int a = trans[e], b = trans[E + e];
    __shared__ int found;
    if (threadIdx.x == 0) found = 0;
    __syncthreads();
    for (int j = threadIdx.x; j < E; j += blockDim.x)
        if (trans[j] == b && trans[E + j] == a) found = 1;   // benign race
    __syncthreads();
    if (threadIdx.x == 0) hr[e] = found;
}

__global__ void build_eraw(const float* __restrict__ data, const int* __restrict__ trans,
                           const int* __restrict__ hr, short* __restrict__ eraw, int E)
{
    int e = blockIdx.x, c = threadIdx.x;  // blockDim = 32
    int t0 = trans[e], t1 = trans[E + e];
    short* r = eraw + (size_t)e * 128;
    if (c < 20) {
        float x0 = data[t0 * 20 + c];
        float x1 = data[t1 * 20 + c];
        float h  = hr[e] ? 1.0f : 0.0f;
        r[c]       = f2bf(x1);
        r[20 + c]  = f2bf(x0);
        r[40 + c]  = f2bf(h * x0);
        r[60 + c]  = f2bf(h * x1);
        r[80 + c]  = f2bf(x1 + h * x0);
        r[100 + c] = f2bf(x0 + h * x1);
    } else if (c < 28) {
        r[120 + (c - 20)] = 0;
    }
}

__global__ void pad_data(const float* __restrict__ data, short* __restrict__ dp, int Nn)
{
    int i = blockIdx.x * 256 + threadIdx.x;
    if (i >= Nn * 64) return;
    int r = i >> 6, c = i & 63;
    dp[i] = (c < 20) ? f2bf(data[r * 20 + c]) : (short)0;
}

__global__ void build_src(const int* __restrict__ einx, int* __restrict__ src, int T)
{
    __shared__ int partial[256];
    __shared__ int excl[256];
    int t = threadIdx.x;
    int base = t * 32;
    int cnt = 0;
    for (int i = 0; i < 32; ++i) {
        int idx = base + i;
        if (idx < T) cnt += (einx[idx] == 1);
    }
    partial[t] = cnt;
    __syncthreads();
    if (t == 0) {
        int s = 0;
        for (int i = 0; i < 256; ++i) { excl[i] = s; s += partial[i]; }
    }
    __syncthreads();
    int ce = excl[t];
    int cn = base - ce;
    for (int i = 0; i < 32; ++i) {
        int idx = base + i;
        if (idx >= T) break;
        if (einx[idx] == 1) { src[idx] = N_NODES + ce; ce++; }
        else                { src[idx] = cn; cn++; }
    }
}

__global__ void gather_x(const short* __restrict__ nfeat, const short* __restrict__ efeat,
                         const int* __restrict__ src, short* __restrict__ x)
{
    int i = blockIdx.x * 256 + threadIdx.x;    // over 8000*96 bf16x8 chunks
    int r = i / 96, c = i % 96;
    int s = src[r];
    const bf16x8* rowp = (s >= N_NODES)
        ? reinterpret_cast<const bf16x8*>(efeat + (size_t)(s - N_NODES) * HID)
        : reinterpret_cast<const bf16x8*>(nfeat + (size_t)s * HID);
    reinterpret_cast<bf16x8*>(x)[i] = rowp[c];
}

__global__ void h1w2_kernel(const float* __restrict__ h1, const float* __restrict__ w2,
                            float* __restrict__ hw)
{
    int wave = threadIdx.x >> 6, lane = threadIdx.x & 63;
    int row = blockIdx.x * 4 + wave;
    const float* hp = h1 + (size_t)row * HID;
    float a0 = 0.0f, a1 = 0.0f;
    for (int k = lane; k < HID; k += 64) {
        float h = hp[k];
        a0 += h * w2[k * 2];
        a1 += h * w2[k * 2 + 1];
    }
    for (int off = 32; off > 0; off >>= 1) {
        a0 += __shfl_down(a0, off);
        a1 += __shfl_down(a1, off);
    }
    if (lane == 0) { hw[row * 2] = a0; hw[row * 2 + 1] = a1; }
}

__global__ __launch_bounds__(256) void adj_hw_bf(const short* __restrict__ A,
    const float* __restrict__ hw, const float* __restrict__ b2, float* __restrict__ logits)
{
    int row = blockIdx.x;
    const short* ar = A + (size_t)row * T_ALL;
    float a0 = 0.0f, a1 = 0.0f;
    for (int c = threadIdx.x; c < 1000; c += 256) {
        bf16x8 v = *reinterpret_cast<const bf16x8*>(ar + c * 8);
#pragma unroll
        for (int j = 0; j < 8; ++j) {
            float av = bf2f(v[j]);
            int k = c * 8 + j;
            a0 += av * hw[k * 2];
            a1 += av * hw[k * 2 + 1];
        }
    }
    __shared__ float s0[256], s1[256];
    s0[threadIdx.x] = a0; s1[threadIdx.x] = a1;
    __syncthreads();
    for (int o = 128; o > 0; o >>= 1) {
        if (threadIdx.x < o) {
            s0[threadIdx.x] += s0[threadIdx.x + o];
            s1[threadIdx.x] += s1[threadIdx.x + o];
        }
        __syncthreads();
    }
    if (threadIdx.x == 0) {
        logits[row * 2]     = s0[0] + b2[0];
        logits[row * 2 + 1] = s1[0] + b2[1];
    }
}

__global__ __launch_bounds__(256) void adj_hw_f32(const float* __restrict__ A,
    const float* __restrict__ hw, const float* __restrict__ b2, float* __restrict__ logits)
{
    int row = blockIdx.x;
    const float* ar = A + (size_t)row * T_ALL;
    float a0 = 0.0f, a1 = 0.0f;
    for (int k = threadIdx.x; k < T_ALL; k += 256) {
        float v = ar[k];
        a0 += v * hw[k * 2];
        a1 += v * hw[k * 2 + 1];
    }
    __shared__ float s0[256], s1[256];
    s0[threadIdx.x] = a0; s1[threadIdx.x] = a1;
    __syncthreads();
    for (int o = 128; o > 0; o >>= 1) {
        if (threadIdx.x < o) {
            s0[threadIdx.x] += s0[threadIdx.x + o];
            s1[threadIdx.x] += s1[threadIdx.x + o];
        }
        __syncthreads();
    }
    if (threadIdx.x == 0) {
        logits[row * 2]     = s0[0] + b2[0];
        logits[row * 2 + 1] = s1[0] + b2[1];
    }
}

__global__ __launch_bounds__(256) void loss_kernel(const float* __restrict__ logits,
    const int* __restrict__ label, const float* __restrict__ mask, float* __restrict__ outp)
{
    __shared__ float sc[256], sm[256];
    float ac = 0.0f, am = 0.0f;
    for (int i = threadIdx.x; i < T_ALL; i += 256) {
        float l0 = logits[i * 2], l1 = logits[i * 2 + 1];
        float mx = fmaxf(l0, l1);
        float lse = mx + logf(expf(l0 - mx) + expf(l1 - mx));
        float li = label[i] ? l1 : l0;
        ac += (lse - li) * mask[i];
        am += mask[i];
    }
    sc[threadIdx.x] = ac; sm[threadIdx.x] = am;
    __syncthreads();
    for (int o = 128; o > 0; o >>= 1) {
        if (threadIdx.x < o) {
            sc[threadIdx.x] += sc[threadIdx.x + o];
            sm[threadIdx.x] += sm[threadIdx.x + o];
        }
        __syncthreads();
    }
    if (threadIdx.x == 0) *outp = sc[0] / fmaxf(sm[0], 1.0f);
}

// ---------------- launch ---------------------------------------------------

extern "C" void kernel_launch(void* const* d_in, const int* in_sizes, int n_in,
                              void* d_out, int out_size, void* d_ws, size_t ws_size,
                              hipStream_t stream)
{
    (void)in_sizes; (void)n_in; (void)out_size;

    const float* data  = (const float*)d_in[0];
    const float* adj   = (const float*)d_in[2];
    const int*   trans = (const int*)d_in[3];
    const int*   einx  = (const int*)d_in[4];
    const int*   label = (const int*)d_in[5];
    const float* mask  = (const float*)d_in[6];
    const float* w1    = (const float*)d_in[7];
    const float* b1    = (const float*)d_in[8];
    const float* w2    = (const float*)d_in[9];
    const float* b2    = (const float*)d_in[10];
    const float* w21   = (const float*)d_in[11];
    const float* b21   = (const float*)d_in[12];
    const float* w22   = (const float*)d_in[13];
    const float* b22   = (const float*)d_in[14];
    const float* gw1   = (const float*)d_in[15];
    const float* gb1   = (const float*)d_in[16];
    const float* gw2   = (const float*)d_in[17];
    const float* gb2   = (const float*)d_in[18];

    char* W = (char*)d_ws;
    // transient low region (dead before adj bf16 conversion on big paths)
    short* w1T   = (short*)(W + 0);          // 768*128
    short* w2T   = (short*)(W + 196608);     // 768*768
    short* w21T  = (short*)(W + 1376256);    // 768*64
    short* w22T  = (short*)(W + 1474560);    // 768*768
    short* gw1T  = (short*)(W + 2654208);    // 768*768
    short* eraw  = (short*)(W + 3833856);    // 4000*128
    short* datap = (short*)(W + 4857856);    // 4000*64
    short* C1    = (short*)(W + 5369856);    // 4000*768
    short* efeat = (short*)(W + 11513856);   // 4000*768
    short* nfeat = (short*)(W + 17657856);   // 4000*768
    short* xbuf  = (short*)(W + 23801856);   // 8000*768
    int*   hr    = (int*)(W + 48377856);     // 4000
    int*   src   = (int*)(W + 48393856);     // 8000

    const bool mid  = (ws_size >= (size_t)140352000);
    const bool big2 = (ws_size >= (size_t)189504000);
    short* adjbf = (short*)W;                // big paths: [0, 128MB)
    short* xwT;  float* hwbuf;  short* parts = nullptr;
    if (mid) {
        xwT   = (short*)(W + 128000000);     // 768*8000 bf16
        hwbuf = (float*)(W + 140288000);
        if (big2) parts = (short*)(W + 140352000);   // 4 * 8000*768 bf16
    } else {
        xwT   = (short*)(W + 48425856);
        hwbuf = (float*)(W + 60713856);
    }

    float* out    = (float*)d_out;
    float* logits = out;            // [8000,2]
    float* lossp  = out + 16000;    // scalar
    float* h1     = out + 16001;    // [8000,768] f32

    // 1) weight transposes -> bf16 BT layouts
    transpose_pad_bf<<<384, 256, 0, stream>>>(w1, w1T, 120, 768, 128);
    transpose_f2b<<<dim3(24, 24), 256, 0, stream>>>(w2, w2T, 768, 768);
    transpose_pad_bf<<<192, 256, 0, stream>>>(w21, w21T, 20, 768, 64);
    transpose_f2b<<<dim3(24, 24), 256, 0, stream>>>(w22, w22T, 768, 768);
    transpose_f2b<<<dim3(24, 24), 256, 0, stream>>>(gw1, gw1T, 768, 768);

    // 2) edge/node features (bf16)
    has_rev_kernel<<<4000, 256, 0, stream>>>(trans, hr, N_EDGES);
    build_eraw<<<4000, 32, 0, stream>>>(data, trans, hr, eraw, N_EDGES);
    pad_data<<<1000, 256, 0, stream>>>(data, datap, N_NODES);

    // 3) MLPs (bf16 in, bf16 out); grid = (Nblk, Mblk)
    gemm_bf<1, 1, 1, 0, 0><<<dim3(6, 32), 256, 0, stream>>>(eraw, w1T, b1, C1, 4000, 768, 128, 128, 128, 768, 0);
    gemm_bf<1, 0, 1, 0, 0><<<dim3(6, 32), 256, 0, stream>>>(C1, w2T, b2, efeat, 4000, 768, 768, 768, 768, 768, 0);
    gemm_bf<1, 1, 1, 0, 0><<<dim3(6, 32), 256, 0, stream>>>(datap, w21T, b21, C1, 4000, 768, 64, 64, 64, 768, 0);
    gemm_bf<1, 0, 1, 0, 0><<<dim3(6, 32), 256, 0, stream>>>(C1, w22T, b22, nfeat, 4000, 768, 768, 768, 768, 768, 0);

    // 4) interleave to x (bf16)
    build_src<<<1, 256, 0, stream>>>(einx, src, T_ALL);
    gather_x<<<3000, 256, 0, stream>>>(nfeat, efeat, src, xbuf);

    // 5) xwT[768][8000] = gw1^T @ x^T directly (A=gw1T, BT=x); N=8000 has tail
    gemm_bf<0, 0, 1, 0, 0><<<dim3(63, 6), 256, 0, stream>>>(gw1T, xbuf, nullptr, xwT, 768, 8000, 768, 768, 768, 8000, 0);

    if (mid) {
        // 6) adj -> bf16 (overwrites transient region; all dead)
        cvt_bf16<<<31250, 256, 0, stream>>>(adj, adjbf, 8000000);
        if (big2) {
            // 7) h1 partials: split-K=4 (kc64=32 steps of 64), then fused reduce
            gemm_bf<0, 0, 1, 0, 1><<<dim3(6, 63, 4), 256, 0, stream>>>(adjbf, xwT, nullptr, parts, 8000, 768, 8000, 8000, 8000, 768, 32);
            reduce4_bias_relu<<<3000, 256, 0, stream>>>(parts, gb1, h1);
        } else {
            gemm_bf<1, 1, 0, 0, 0><<<dim3(6, 63), 256, 0, stream>>>(adjbf, xwT, gb1, h1, 8000, 768, 8000, 8000, 8000, 768, 0);
        }
        h1w2_kernel<<<2000, 256, 0, stream>>>(h1, gw2, hwbuf);
        adj_hw_bf<<<8000, 256, 0, stream>>>(adjbf, hwbuf, gb2, logits);
    } else {
        gemm_bf<1, 1, 0, 1, 0><<<dim3(6, 63), 256, 0, stream>>>(adj, xwT, gb1, h1, 8000, 768, 8000, 8000, 8000, 768, 0);
        h1w2_kernel<<<2000, 256, 0, stream>>>(h1, gw2, hwbuf);
        adj_hw_f32<<<8000, 256, 0, stream>>>(adj, hwbuf, gb2, logits);
    }
    loss_kernel<<<1, 256, 0, stream>>>(logits, label, mask, lossp);
}

// Round 4
// 431.523 us; speedup vs baseline: 2.5431x; 1.0135x over previous
//
#include <hip/hip_runtime.h>
#include <hip/hip_bf16.h>

#define N_NODES 4000
#define N_EDGES 4000
#define T_ALL   8000
#define HID     768

typedef __attribute__((ext_vector_type(8))) short bf16x8;
typedef __attribute__((ext_vector_type(4))) short s16x4;
typedef __attribute__((ext_vector_type(4))) float f32x4;

__device__ __forceinline__ short f2bf(float f) {
    union { float f; unsigned u; } a; a.f = f;
    unsigned u = a.u;
    unsigned r = (u + 0x7fffu + ((u >> 16) & 1u)) >> 16;   // RNE
    return (short)(r & 0xffffu);
}
__device__ __forceinline__ float bf2f(short s) {
    union { unsigned u; float f; } a;
    a.u = ((unsigned)(unsigned short)s) << 16;
    return a.f;
}
__device__ __forceinline__ void gload_lds16(const void* g, void* l) {
    __builtin_amdgcn_global_load_lds(
        (const __attribute__((address_space(1))) void*)g,
        (__attribute__((address_space(3))) void*)l, 16, 0, 0);
}

// ---------------- GEMM: C[M,N] = A[M,K] * B  (B given as BT[N,K], bf16) ----
// 128x128 tile, BK=64, 256 threads (4 waves 2x2), double-buffered LDS with
// counted-vmcnt pipeline (loads stay in flight across raw barriers — T4).
// Grid: x = N-blocks (fastest), y = M-blocks, z = K-splits (SPLIT=1).
// K%64==0. M,N arbitrary (clamped staging + guarded writes).
// AF32=1: A is f32, reg-staged + converted (safe __syncthreads loop).
// SPLIT=1: write bf16 partials at Cv + z*M*ldc, no bias/relu.
template<int BIAS, int RELU, int OUTBF, int AF32, int SPLIT>
__global__ __launch_bounds__(256) void gemm_bf(
    const void* __restrict__ Av, const short* __restrict__ BT,
    const float* __restrict__ bias, void* __restrict__ Cv,
    int M, int N, int K, int lda, int ldbt, int ldc, int kc64)
{
    __shared__ __align__(16) short As[2][128 * 64];
    __shared__ __align__(16) short Bs[2][128 * 64];
    const int t    = threadIdx.x;
    const int lane = t & 63;
    const int wave = t >> 6;
    const int wr   = (wave >> 1) << 6;
    const int wc   = (wave & 1) << 6;
    const int lrow = lane & 15;
    const int kgrp = lane >> 4;
    const int bm0  = blockIdx.y << 7;
    const int bn0  = blockIdx.x << 7;
    const short* Ab = (const short*)Av;
    const float* Af = (const float*)Av;

    int kbeg = 0, nk = K >> 6;
    if constexpr (SPLIT) {
        kbeg = blockIdx.z * kc64 * 64;
        int rem = (K - kbeg) >> 6;
        nk = rem < kc64 ? rem : kc64;
    }

    auto stage = [&](int kt, int buf) {
        const int k0 = kbeg + (kt << 6);
#pragma unroll
        for (int i = 0; i < 4; ++i) {
            int f = t + (i << 8);
            int row = f >> 3, slot = f & 7;
            int gb = bn0 + row; gb = (gb < N) ? gb : (N - 1);
            gload_lds16(BT + (size_t)gb * ldbt + k0 + ((slot ^ (row & 7)) << 3),
                        &Bs[buf][((i << 8) + (wave << 6)) * 8]);
        }
        if constexpr (!AF32) {
#pragma unroll
            for (int i = 0; i < 4; ++i) {
                int f = t + (i << 8);
                int row = f >> 3, slot = f & 7;
                int ga = bm0 + row; ga = (ga < M) ? ga : (M - 1);
                gload_lds16(Ab + (size_t)ga * lda + k0 + ((slot ^ (row & 7)) << 3),
                            &As[buf][((i << 8) + (wave << 6)) * 8]);
            }
        } else {
#pragma unroll
            for (int i = 0; i < 4; ++i) {
                int f = t + (i << 8);
                int row = f >> 3, c8 = f & 7;
                int ga = bm0 + row; ga = (ga < M) ? ga : (M - 1);
                const float* ap = Af + (size_t)ga * lda + k0 + (c8 << 3);
                float4 v0 = *reinterpret_cast<const float4*>(ap);
                float4 v1 = *reinterpret_cast<const float4*>(ap + 4);
                union { bf16x8 v; short s[8]; } u;
                u.s[0] = f2bf(v0.x); u.s[1] = f2bf(v0.y); u.s[2] = f2bf(v0.z); u.s[3] = f2bf(v0.w);
                u.s[4] = f2bf(v1.x); u.s[5] = f2bf(v1.y); u.s[6] = f2bf(v1.z); u.s[7] = f2bf(v1.w);
                *reinterpret_cast<bf16x8*>(&As[buf][row * 64 + ((c8 ^ (row & 7)) << 3)]) = u.v;
            }
        }
    };

    f32x4 acc[4][4];
#pragma unroll
    for (int m = 0; m < 4; ++m)
#pragma unroll
        for (int n = 0; n < 4; ++n) acc[m][n] = (f32x4)(0.0f);

    auto compute = [&](int buf) {
#pragma unroll
        for (int kk = 0; kk < 2; ++kk) {
            bf16x8 af[4], bfv[4];
#pragma unroll
            for (int m = 0; m < 4; ++m) {
                int r = wr + m * 16 + lrow;
                af[m] = *reinterpret_cast<const bf16x8*>(
                    &As[buf][r * 64 + (((kk * 4 + kgrp) ^ (r & 7)) << 3)]);
            }
#pragma unroll
            for (int n = 0; n < 4; ++n) {
                int r = wc + n * 16 + lrow;
                bfv[n] = *reinterpret_cast<const bf16x8*>(
                    &Bs[buf][r * 64 + (((kk * 4 + kgrp) ^ (r & 7)) << 3)]);
            }
#pragma unroll
            for (int m = 0; m < 4; ++m)
#pragma unroll
                for (int n = 0; n < 4; ++n)
                    acc[m][n] = __builtin_amdgcn_mfma_f32_16x16x32_bf16(
                        af[m], bfv[n], acc[m][n], 0, 0, 0);
        }
    };

    if constexpr (!AF32) {
        // counted-vmcnt pipeline: both tiles' loads in flight, never drain to 0
        stage(0, 0);
        if (nk > 1) stage(1, 1);
        for (int kt = 0; kt < nk - 1; ++kt) {
            asm volatile("s_waitcnt vmcnt(8)" ::: "memory");   // tile kt landed
            __builtin_amdgcn_s_barrier();                      // staged for all waves
            compute(kt & 1);
            __builtin_amdgcn_s_barrier();                      // all reads of buf done
            if (kt + 2 < nk) stage(kt + 2, kt & 1);            // overwrite just-read buf
        }
        asm volatile("s_waitcnt vmcnt(0)" ::: "memory");
        __builtin_amdgcn_s_barrier();
        compute((nk - 1) & 1);
    } else {
        stage(0, 0);
        __syncthreads();
        int cur = 0;
        for (int kt = 0; kt < nk; ++kt) {
            if (kt + 1 < nk) stage(kt + 1, cur ^ 1);
            compute(cur);
            __syncthreads();
            cur ^= 1;
        }
    }

    // epilogue: C/D layout col = lane&15, row = (lane>>4)*4 + j
    short* Cb = (short*)Cv;
    float* Cf = (float*)Cv;
    if constexpr (SPLIT) Cb += (size_t)blockIdx.z * M * ldc;
#pragma unroll
    for (int m = 0; m < 4; ++m) {
        int rbase = bm0 + wr + m * 16 + kgrp * 4;
#pragma unroll
        for (int n = 0; n < 4; ++n) {
            int col = bn0 + wc + n * 16 + lrow;
            if (col >= N) continue;
            float bv = BIAS ? bias[col] : 0.0f;
#pragma unroll
            for (int j = 0; j < 4; ++j) {
                int r = rbase + j;
                if (r < M) {
                    float v = acc[m][n][j] + bv;
                    if (RELU) v = fmaxf(v, 0.0f);
                    if (OUTBF) Cb[(size_t)r * ldc + col] = f2bf(v);
                    else       Cf[(size_t)r * ldc + col] = v;
                }
            }
        }
    }
}

// One block per row: h1[r] = relu(sum_z partial_z[r] + bias); hw[r] = h1[r] @ w2
// partials bf16 [4][8000*768]; 192 threads x 4 cols.
__global__ __launch_bounds__(192) void reduce4_h1_hw(
    const short* __restrict__ p, const float* __restrict__ bias,
    const float* __restrict__ w2, float* __restrict__ h1, float* __restrict__ hw)
{
    int r = blockIdx.x, t = threadIdx.x;
    int c0 = t * 4;
    size_t base = (size_t)r * 768 + c0;
    float a[4];
#pragma unroll
    for (int j = 0; j < 4; ++j) a[j] = bias[c0 + j];
#pragma unroll
    for (int z = 0; z < 4; ++z) {
        s16x4 v = *reinterpret_cast<const s16x4*>(p + (size_t)z * 6144000 + base);
#pragma unroll
        for (int j = 0; j < 4; ++j) a[j] += bf2f(v[j]);
    }
    float d0 = 0.0f, d1 = 0.0f;
    float4 o;
#pragma unroll
    for (int j = 0; j < 4; ++j) {
        float v = fmaxf(a[j], 0.0f);
        ((float*)&o)[j] = v;
        d0 += v * w2[(c0 + j) * 2];
        d1 += v * w2[(c0 + j) * 2 + 1];
    }
    *reinterpret_cast<float4*>(h1 + base) = o;
    // reduce 192 threads: wave shuffle then cross-wave via LDS
#pragma unroll
    for (int off = 32; off > 0; off >>= 1) {
        d0 += __shfl_down(d0, off);
        d1 += __shfl_down(d1, off);
    }
    __shared__ float s0[3], s1[3];
    int wv = t >> 6, ln = t & 63;
    if (ln == 0) { s0[wv] = d0; s1[wv] = d1; }
    __syncthreads();
    if (t == 0) {
        hw[r * 2]     = s0[0] + s0[1] + s0[2];
        hw[r * 2 + 1] = s1[0] + s1[1] + s1[2];
    }
}

// ---------------- small kernels -------------------------------------------

__global__ void transpose_pad_bf(const float* __restrict__ in, short* __restrict__ out,
                                 int K, int N, int Kp)
{
    int i = blockIdx.x * 256 + threadIdx.x;
    if (i >= N * Kp) return;
    int n = i / Kp, k = i % Kp;
    out[i] = (k < K) ? f2bf(in[k * N + n]) : (short)0;
}

__global__ __launch_bounds__(256) void transpose_f2b(const float* __restrict__ in,
                                                     short* __restrict__ out, int R, int C)
{
    __shared__ float tile[32][33];
    int c0 = blockIdx.x << 5, r0 = blockIdx.y << 5;
    int tx = threadIdx.x & 31, ty = threadIdx.x >> 5;
#pragma unroll
    for (int i = ty; i < 32; i += 8)
        tile[i][tx] = in[(size_t)(r0 + i) * C + c0 + tx];
    __syncthreads();
#pragma unroll
    for (int i = ty; i < 32; i += 8)
        out[(size_t)(c0 + i) * R + r0 + tx] = f2bf(tile[tx][i]);
}

__global__ void cvt_bf16(const float* __restrict__ in, short* __restrict__ out, int n8)
{
    int i = blockIdx.x * 256 + threadIdx.x;
    if (i >= n8) return;
    float4 v0 = *reinterpret_cast<const float4*>(in + (size_t)i * 8);
    float4 v1 = *reinterpret_cast<const float4*>(in + (size_t)i * 8 + 4);
    union { bf16x8 v; short s[8]; } u;
    u.s[0] = f2bf(v0.x); u.s[1] = f2bf(v0.y); u.s[2] = f2bf(v0.z); u.s[3] = f2bf(v0.w);
    u.s[4] = f2bf(v1.x); u.s[5] = f2bf(v1.y); u.s[6] = f2bf(v1.z); u.s[7] = f2bf(v1.w);
    *reinterpret_cast<bf16x8*>(out + (size_t)i * 8) = u.v;
}

__global__ void has_rev_kernel(const int* __restrict__ trans, int* __restrict__ hr, int E)
{
    int e = blockIdx.x;
    int a = trans[e], b = trans[E + e];
    __shared__ int found;
    if (threadIdx.x == 0) found = 0;
    __syncthreads();
    for (int j = threadIdx.x; j < E; j += blockDim.x)
        if (trans[j] == b && trans[E + j] == a) found = 1;   // benign race
    __syncthreads();
    if (threadIdx.x == 0) hr[e] = found;
}

__global__ void build_eraw(const float* __restrict__ data, const int* __restrict__ trans,
                           const int* __restrict__ hr, short* __restrict__ eraw, int E)
{
    int e = blockIdx.x, c = threadIdx.x;  // blockDim = 32
    int t0 = trans[e], t1 = trans[E + e];
    short* r = eraw + (size_t)e * 128;
    if (c < 20) {
        float x0 = data[t0 * 20 + c];
        float x1 = data[t1 * 20 + c];
        float h  = hr[e] ? 1.0f : 0.0f;
        r[c]       = f2bf(x1);
        r[20 + c]  = f2bf(x0);
        r[40 + c]  = f2bf(h * x0);
        r[60 + c]  = f2bf(h * x1);
        r[80 + c]  = f2bf(x1 + h * x0);
        r[100 + c] = f2bf(x0 + h * x1);
    } else if (c < 28) {
        r[120 + (c - 20)] = 0;
    }
}

__global__ void pad_data(const float* __restrict__ data, short* __restrict__ dp, int Nn)
{
    int i = blockIdx.x * 256 + threadIdx.x;
    if (i >= Nn * 64) return;
    int r = i >> 6, c = i & 63;
    dp[i] = (c < 20) ? f2bf(data[r * 20 + c]) : (short)0;
}

__global__ void build_src(const int* __restrict__ einx, int* __restrict__ src, int T)
{
    __shared__ int partial[256];
    __shared__ int excl[256];
    int t = threadIdx.x;
    int base = t * 32;
    int cnt = 0;
    for (int i = 0; i < 32; ++i) {
        int idx = base + i;
        if (idx < T) cnt += (einx[idx] == 1);
    }
    partial[t] = cnt;
    __syncthreads();
    if (t == 0) {
        int s = 0;
        for (int i = 0; i < 256; ++i) { excl[i] = s; s += partial[i]; }
    }
    __syncthreads();
    int ce = excl[t];
    int cn = base - ce;
    for (int i = 0; i < 32; ++i) {
        int idx = base + i;
        if (idx >= T) break;
        if (einx[idx] == 1) { src[idx] = N_NODES + ce; ce++; }
        else                { src[idx] = cn; cn++; }
    }
}

__global__ void gather_x(const short* __restrict__ nfeat, const short* __restrict__ efeat,
                         const int* __restrict__ src, short* __restrict__ x)
{
    int i = blockIdx.x * 256 + threadIdx.x;    // over 8000*96 bf16x8 chunks
    int r = i / 96, c = i % 96;
    int s = src[r];
    const bf16x8* rowp = (s >= N_NODES)
        ? reinterpret_cast<const bf16x8*>(efeat + (size_t)(s - N_NODES) * HID)
        : reinterpret_cast<const bf16x8*>(nfeat + (size_t)s * HID);
    reinterpret_cast<bf16x8*>(x)[i] = rowp[c];
}

__global__ void h1w2_kernel(const float* __restrict__ h1, const float* __restrict__ w2,
                            float* __restrict__ hw)
{
    int wave = threadIdx.x >> 6, lane = threadIdx.x & 63;
    int row = blockIdx.x * 4 + wave;
    const float* hp = h1 + (size_t)row * HID;
    float a0 = 0.0f, a1 = 0.0f;
    for (int k = lane; k < HID; k += 64) {
        float h = hp[k];
        a0 += h * w2[k * 2];
        a1 += h * w2[k * 2 + 1];
    }
    for (int off = 32; off > 0; off >>= 1) {
        a0 += __shfl_down(a0, off);
        a1 += __shfl_down(a1, off);
    }
    if (lane == 0) { hw[row * 2] = a0; hw[row * 2 + 1] = a1; }
}

__global__ __launch_bounds__(256) void adj_hw_bf(const short* __restrict__ A,
    const float* __restrict__ hw, const float* __restrict__ b2, float* __restrict__ logits)
{
    int row = blockIdx.x;
    const short* ar = A + (size_t)row * T_ALL;
    float a0 = 0.0f, a1 = 0.0f;
    for (int c = threadIdx.x; c < 1000; c += 256) {
        bf16x8 v = *reinterpret_cast<const bf16x8*>(ar + c * 8);
#pragma unroll
        for (int j = 0; j < 8; ++j) {
            float av = bf2f(v[j]);
            int k = c * 8 + j;
            a0 += av * hw[k * 2];
            a1 += av * hw[k * 2 + 1];
        }
    }
    __shared__ float s0[256], s1[256];
    s0[threadIdx.x] = a0; s1[threadIdx.x] = a1;
    __syncthreads();
    for (int o = 128; o > 0; o >>= 1) {
        if (threadIdx.x < o) {
            s0[threadIdx.x] += s0[threadIdx.x + o];
            s1[threadIdx.x] += s1[threadIdx.x + o];
        }
        __syncthreads();
    }
    if (threadIdx.x == 0) {
        logits[row * 2]     = s0[0] + b2[0];
        logits[row * 2 + 1] = s1[0] + b2[1];
    }
}

__global__ __launch_bounds__(256) void adj_hw_f32(const float* __restrict__ A,
    const float* __restrict__ hw, const float* __restrict__ b2, float* __restrict__ logits)
{
    int row = blockIdx.x;
    const float* ar = A + (size_t)row * T_ALL;
    float a0 = 0.0f, a1 = 0.0f;
    for (int k = threadIdx.x; k < T_ALL; k += 256) {
        float v = ar[k];
        a0 += v * hw[k * 2];
        a1 += v * hw[k * 2 + 1];
    }
    __shared__ float s0[256], s1[256];
    s0[threadIdx.x] = a0; s1[threadIdx.x] = a1;
    __syncthreads();
    for (int o = 128; o > 0; o >>= 1) {
        if (threadIdx.x < o) {
            s0[threadIdx.x] += s0[threadIdx.x + o];
            s1[threadIdx.x] += s1[threadIdx.x + o];
        }
        __syncthreads();
    }
    if (threadIdx.x == 0) {
        logits[row * 2]     = s0[0] + b2[0];
        logits[row * 2 + 1] = s1[0] + b2[1];
    }
}

__global__ __launch_bounds__(256) void loss_kernel(const float* __restrict__ logits,
    const int* __restrict__ label, const float* __restrict__ mask, float* __restrict__ outp)
{
    __shared__ float sc[256], sm[256];
    float ac = 0.0f, am = 0.0f;
    for (int i = threadIdx.x; i < T_ALL; i += 256) {
        float l0 = logits[i * 2], l1 = logits[i * 2 + 1];
        float mx = fmaxf(l0, l1);
        float lse = mx + logf(expf(l0 - mx) + expf(l1 - mx));
        float li = label[i] ? l1 : l0;
        ac += (lse - li) * mask[i];
        am += mask[i];
    }
    sc[threadIdx.x] = ac; sm[threadIdx.x] = am;
    __syncthreads();
    for (int o = 128; o > 0; o >>= 1) {
        if (threadIdx.x < o) {
            sc[threadIdx.x] += sc[threadIdx.x + o];
            sm[threadIdx.x] += sm[threadIdx.x + o];
        }
        __syncthreads();
    }
    if (threadIdx.x == 0) *outp = sc[0] / fmaxf(sm[0], 1.0f);
}

// ---------------- launch ---------------------------------------------------

extern "C" void kernel_launch(void* const* d_in, const int* in_sizes, int n_in,
                              void* d_out, int out_size, void* d_ws, size_t ws_size,
                              hipStream_t stream)
{
    (void)in_sizes; (void)n_in; (void)out_size;

    const float* data  = (const float*)d_in[0];
    const float* adj   = (const float*)d_in[2];
    const int*   trans = (const int*)d_in[3];
    const int*   einx  = (const int*)d_in[4];
    const int*   label = (const int*)d_in[5];
    const float* mask  = (const float*)d_in[6];
    const float* w1    = (const float*)d_in[7];
    const float* b1    = (const float*)d_in[8];
    const float* w2    = (const float*)d_in[9];
    const float* b2    = (const float*)d_in[10];
    const float* w21   = (const float*)d_in[11];
    const float* b21   = (const float*)d_in[12];
    const float* w22   = (const float*)d_in[13];
    const float* b22   = (const float*)d_in[14];
    const float* gw1   = (const float*)d_in[15];
    const float* gb1   = (const float*)d_in[16];
    const float* gw2   = (const float*)d_in[17];
    const float* gb2   = (const float*)d_in[18];

    char* W = (char*)d_ws;
    // transient low region (dead before adj bf16 conversion on big paths)
    short* w1T   = (short*)(W + 0);          // 768*128
    short* w2T   = (short*)(W + 196608);     // 768*768
    short* w21T  = (short*)(W + 1376256);    // 768*64
    short* w22T  = (short*)(W + 1474560);    // 768*768
    short* gw1T  = (short*)(W + 2654208);    // 768*768
    short* eraw  = (short*)(W + 3833856);    // 4000*128
    short* datap = (short*)(W + 4857856);    // 4000*64
    short* C1    = (short*)(W + 5369856);    // 4000*768
    short* efeat = (short*)(W + 11513856);   // 4000*768
    short* nfeat = (short*)(W + 17657856);   // 4000*768
    short* xbuf  = (short*)(W + 23801856);   // 8000*768
    int*   hr    = (int*)(W + 48377856);     // 4000
    int*   src   = (int*)(W + 48393856);     // 8000

    const bool mid  = (ws_size >= (size_t)140352000);
    const bool big2 = (ws_size >= (size_t)189504000);
    short* adjbf = (short*)W;                // big paths: [0, 128MB)
    short* xwT;  float* hwbuf;  short* parts = nullptr;
    if (mid) {
        xwT   = (short*)(W + 128000000);     // 768*8000 bf16
        hwbuf = (float*)(W + 140288000);
        if (big2) parts = (short*)(W + 140352000);   // 4 * 8000*768 bf16
    } else {
        xwT   = (short*)(W + 48425856);
        hwbuf = (float*)(W + 60713856);
    }

    float* out    = (float*)d_out;
    float* logits = out;            // [8000,2]
    float* lossp  = out + 16000;    // scalar
    float* h1     = out + 16001;    // [8000,768] f32

    // 1) weight transposes -> bf16 BT layouts
    transpose_pad_bf<<<384, 256, 0, stream>>>(w1, w1T, 120, 768, 128);
    transpose_f2b<<<dim3(24, 24), 256, 0, stream>>>(w2, w2T, 768, 768);
    transpose_pad_bf<<<192, 256, 0, stream>>>(w21, w21T, 20, 768, 64);
    transpose_f2b<<<dim3(24, 24), 256, 0, stream>>>(w22, w22T, 768, 768);
    transpose_f2b<<<dim3(24, 24), 256, 0, stream>>>(gw1, gw1T, 768, 768);

    // 2) edge/node features (bf16)
    has_rev_kernel<<<4000, 256, 0, stream>>>(trans, hr, N_EDGES);
    build_eraw<<<4000, 32, 0, stream>>>(data, trans, hr, eraw, N_EDGES);
    pad_data<<<1000, 256, 0, stream>>>(data, datap, N_NODES);

    // 3) MLPs (bf16 in, bf16 out); grid = (Nblk, Mblk)
    gemm_bf<1, 1, 1, 0, 0><<<dim3(6, 32), 256, 0, stream>>>(eraw, w1T, b1, C1, 4000, 768, 128, 128, 128, 768, 0);
    gemm_bf<1, 0, 1, 0, 0><<<dim3(6, 32), 256, 0, stream>>>(C1, w2T, b2, efeat, 4000, 768, 768, 768, 768, 768, 0);
    gemm_bf<1, 1, 1, 0, 0><<<dim3(6, 32), 256, 0, stream>>>(datap, w21T, b21, C1, 4000, 768, 64, 64, 64, 768, 0);
    gemm_bf<1, 0, 1, 0, 0><<<dim3(6, 32), 256, 0, stream>>>(C1, w22T, b22, nfeat, 4000, 768, 768, 768, 768, 768, 0);

    // 4) interleave to x (bf16)
    build_src<<<1, 256, 0, stream>>>(einx, src, T_ALL);
    gather_x<<<3000, 256, 0, stream>>>(nfeat, efeat, src, xbuf);

    // 5) xwT[768][8000] = gw1^T @ x^T directly (A=gw1T, BT=x); N=8000 has tail
    gemm_bf<0, 0, 1, 0, 0><<<dim3(63, 6), 256, 0, stream>>>(gw1T, xbuf, nullptr, xwT, 768, 8000, 768, 768, 768, 8000, 0);

    if (mid) {
        // 6) adj -> bf16 (overwrites transient region; all dead)
        cvt_bf16<<<31250, 256, 0, stream>>>(adj, adjbf, 8000000);
        if (big2) {
            // 7) h1 partials: split-K=4 (kc64=32 steps of 64), fused reduce + h1w2
            gemm_bf<0, 0, 1, 0, 1><<<dim3(6, 63, 4), 256, 0, stream>>>(adjbf, xwT, nullptr, parts, 8000, 768, 8000, 8000, 8000, 768, 32);
            reduce4_h1_hw<<<8000, 192, 0, stream>>>(parts, gb1, gw2, h1, hwbuf);
        } else {
            gemm_bf<1, 1, 0, 0, 0><<<dim3(6, 63), 256, 0, stream>>>(adjbf, xwT, gb1, h1, 8000, 768, 8000, 8000, 8000, 768, 0);
            h1w2_kernel<<<2000, 256, 0, stream>>>(h1, gw2, hwbuf);
        }
        adj_hw_bf<<<8000, 256, 0, stream>>>(adjbf, hwbuf, gb2, logits);
    } else {
        gemm_bf<1, 1, 0, 1, 0><<<dim3(6, 63), 256, 0, stream>>>(adj, xwT, gb1, h1, 8000, 768, 8000, 8000, 8000, 768, 0);
        h1w2_kernel<<<2000, 256, 0, stream>>>(h1, gw2, hwbuf);
        adj_hw_f32<<<8000, 256, 0, stream>>>(adj, hwbuf, gb2, logits);
    }
    loss_kernel<<<1, 256, 0, stream>>>(logits, label, mask, lossp);
}